// Round 9
// baseline (258.294 us; speedup 1.0000x reference)
//
#include <hip/hip_runtime.h>
#include <hip/hip_bf16.h>
#include <math.h>

typedef __bf16 bf16;
typedef __bf16 bf16x2 __attribute__((ext_vector_type(2)));
typedef __bf16 bf16x4 __attribute__((ext_vector_type(4)));
typedef __bf16 bf16x8 __attribute__((ext_vector_type(8)));
typedef float  f32x4  __attribute__((ext_vector_type(4)));

#define T_SEQ 2048
#define E_DIM 1024
#define H_NUM 16
#define D_DIM 64
#define NDELTA 4095
#define LOG2E 1.4426950408889634f

__device__ __forceinline__ void gld16(const bf16* g, bf16* l) {
  __builtin_amdgcn_global_load_lds((__attribute__((address_space(1))) void*)(g),
                                   (__attribute__((address_space(3))) void*)(l), 16, 0, 0);
}

// ---------------- fp32 -> bf16 cast (hidden_states) ----------------
__global__ void cast_bf16_kernel(const float* __restrict__ src, bf16* __restrict__ dst, int n4) {
  int i = blockIdx.x * blockDim.x + threadIdx.x;
  if (i >= n4) return;
  const float4 v = reinterpret_cast<const float4*>(src)[i];
  bf16x4 o;
  o[0] = (bf16)v.x; o[1] = (bf16)v.y; o[2] = (bf16)v.z; o[3] = (bf16)v.w;
  reinterpret_cast<bf16x4*>(dst)[i] = o;
}

// ---------------- all 4 weight casts in one launch; q/k/v into concat buffer ----------------
__global__ void cast_w_kernel(const float* __restrict__ q_w, const float* __restrict__ k_w,
                              const float* __restrict__ v_w, const float* __restrict__ o_w,
                              bf16* __restrict__ wcat, bf16* __restrict__ wob) {
  int i = blockIdx.x * 256 + threadIdx.x;
  int sel = blockIdx.y;
  const float* src = (sel == 0) ? q_w : (sel == 1) ? k_w : (sel == 2) ? v_w : o_w;
  bf16* dst = (sel < 3) ? (wcat + (size_t)sel * 1048576) : wob;
  const float4 v = reinterpret_cast<const float4*>(src)[i];
  bf16x4 o;
  o[0] = (bf16)v.x; o[1] = (bf16)v.y; o[2] = (bf16)v.z; o[3] = (bf16)v.w;
  reinterpret_cast<bf16x4*>(dst)[i] = o;
}

// ---------------- position-bias table pbt[h][delta+2047] ----------------
__global__ void pb_kernel(const float* __restrict__ rel_embed, float* __restrict__ pbt) {
  int dd = blockIdx.x * 64 + threadIdx.x;
  if (dd >= NDELTA) return;
  int delta = dd - (T_SEQ - 1);
  int bucket = (delta > 0) ? 160 : 0;
  int rel = abs(delta);
  int v;
  if (rel < 80) {
    v = rel;
  } else {
    float rf = (float)(rel < 1 ? 1 : rel);
    float lf = logf(rf / 80.0f) * (80.0f / 2.302585092994046f);
    int lg = 80 + (int)lf;
    v = lg < 159 ? lg : 159;
  }
  bucket += v;
#pragma unroll
  for (int h = 0; h < H_NUM; h++)
    pbt[h * NDELTA + dd] = rel_embed[bucket * H_NUM + h];
}

// ---------------- gate (output pre-multiplied by LOG2E) ----------------
__global__ __launch_bounds__(256)
void gate_kernel(const float* __restrict__ hs, const float* __restrict__ gru_w,
                 const float* __restrict__ gru_b, const float* __restrict__ gconst,
                 float* __restrict__ gate)
{
  __shared__ float w[512];
  int tid = threadIdx.x;
  w[tid] = gru_w[tid];
  w[tid + 256] = gru_w[tid + 256];
  __syncthreads();
  int idx = blockIdx.x * 256 + tid;
  int h  = idx & 15;
  int bt = idx >> 4;
  const float* x = hs + (size_t)bt * E_DIM + h * D_DIM;
  float acc[8] = {0,0,0,0,0,0,0,0};
  for (int d = 0; d < 64; d += 4) {
    float4 xv = *(const float4*)&x[d];
#pragma unroll
    for (int e = 0; e < 8; e++) {
      acc[e] += xv.x * w[e*64+d] + xv.y * w[e*64+d+1]
              + xv.z * w[e*64+d+2] + xv.w * w[e*64+d+3];
    }
  }
  float p0 = acc[0]+acc[1]+acc[2]+acc[3] + gru_b[0]+gru_b[1]+gru_b[2]+gru_b[3];
  float p1 = acc[4]+acc[5]+acc[6]+acc[7] + gru_b[4]+gru_b[5]+gru_b[6]+gru_b[7];
  float ga = 1.0f / (1.0f + expf(-p0));
  float gb = 1.0f / (1.0f + expf(-p1));
  float g = (ga * (gb * gconst[h] - 1.0f) + 2.0f) * LOG2E;
  int bb = bt >> 11;
  int t  = bt & (T_SEQ - 1);
  gate[((size_t)(bb * H_NUM + h)) * T_SEQ + t] = g;
}

// ---------------- GEMM v3: double-buffered global_load_lds, BMx128x32 ----------------
// MODE 0: O-proj -> f32 out0, bias b0.  MODE 1: fused QKV, seg = n0>>10.
template<int MODE, int BM>
__global__ __launch_bounds__(256)
void gemm3_kernel(const bf16* __restrict__ A, const bf16* __restrict__ W,
                  const float* __restrict__ b0, const float* __restrict__ b1,
                  const float* __restrict__ b2, float qalpha,
                  void* __restrict__ out0, void* __restrict__ out1, void* __restrict__ out2)
{
  constexpr int AM = (BM == 128) ? 4 : 2;
  __shared__ bf16 As[2][BM * 32];
  __shared__ bf16 Bs[2][128 * 32];
  const int tid  = threadIdx.x;
  const int lane = tid & 63;
  const int wave = tid >> 6;
  const int m0 = blockIdx.y * BM;
  const int n0 = blockIdx.x * 128;
  const int wm = (wave >> 1) * (AM * 16);
  const int wn = (wave & 1) * 64;
  const int qd = lane >> 4;
  const int lm = lane & 15;

  const int row4 = lane >> 2;
  const int col8 = (lane & 3) * 8;
  const bf16* gA0 = A + (size_t)(m0 + wave * (BM / 4) + row4) * 1024 + col8;
  const bf16* gB0 = W + (size_t)(n0 + wave * 32 + row4) * 1024 + col8;
  const bf16* gB1 = gB0 + (size_t)16 * 1024;
  bf16* lA = (bf16*)As + wave * (BM / 4) * 32;
  bf16* lB = (bf16*)Bs + wave * 1024;

  // stage k0=0 into buf 0
  gld16(gA0, lA);
  if (BM == 128) gld16(gA0 + (size_t)16 * 1024, lA + 512);
  gld16(gB0, lB);
  gld16(gB1, lB + 512);
  __syncthreads();

  f32x4 acc[AM][4] = {};

  for (int k0 = 0; k0 < 1024; k0 += 32) {
    const int buf = (k0 >> 5) & 1;
    if (k0 + 32 < 1024) {   // prefetch next tile into the other buffer
      bf16* lA1 = lA + (buf ^ 1) * (BM * 32);
      bf16* lB1 = lB + (buf ^ 1) * (128 * 32);
      gld16(gA0 + k0 + 32, lA1);
      if (BM == 128) gld16(gA0 + (size_t)16 * 1024 + k0 + 32, lA1 + 512);
      gld16(gB0 + k0 + 32, lB1);
      gld16(gB1 + k0 + 32, lB1 + 512);
    }
    bf16x8 af[AM], bfr[4];
#pragma unroll
    for (int i = 0; i < AM; i++)
      af[i]  = *(const bf16x8*)&As[buf][(wm + i * 16 + lm) * 32 + qd * 8];
#pragma unroll
    for (int i = 0; i < 4; i++)
      bfr[i] = *(const bf16x8*)&Bs[buf][(wn + i * 16 + lm) * 32 + qd * 8];
#pragma unroll
    for (int im = 0; im < AM; im++)
#pragma unroll
      for (int in = 0; in < 4; in++)
        acc[im][in] = __builtin_amdgcn_mfma_f32_16x16x32_bf16(af[im], bfr[in], acc[im][in], 0, 0, 0);
    __syncthreads();   // drains vmcnt: prefetch landed; frag reads done
  }

  const int seg = n0 >> 10;
  const float* bias = (MODE == 0) ? b0 : (seg == 0 ? b0 : (seg == 1 ? b1 : b2));
  const float alpha = (MODE == 1 && seg == 0) ? qalpha : 1.0f;

#pragma unroll
  for (int im = 0; im < AM; im++) {
#pragma unroll
    for (int in = 0; in < 4; in++) {
      const int n  = n0 + wn + in * 16 + lm;
      const int n1 = n & 1023;
      const float bv = bias[n1];
      const int mb = m0 + wm + im * 16 + qd * 4;
      if (MODE == 0) {
        float* o = (float*)out0;
#pragma unroll
        for (int r = 0; r < 4; r++)
          o[(size_t)(mb + r) * 1024 + n1] = acc[im][in][r] + bv;
      } else if (seg == 2) {
        const int bb = mb >> 11;
        const int t  = mb & 2047;
        bf16x4 pk;
#pragma unroll
        for (int r = 0; r < 4; r++) pk[r] = (bf16)(acc[im][in][r] + bv);
        *(bf16x4*)&((bf16*)out2)[((size_t)(bb * 1024 + n1)) * 2048 + t] = pk;
      } else {
        bf16* o = (bf16*)(seg == 0 ? out0 : out1);
#pragma unroll
        for (int r = 0; r < 4; r++)
          o[(size_t)(mb + r) * 1024 + n1] = (bf16)((acc[im][in][r] + bv) * alpha);
      }
    }
  }
}

// ---------------- flash attention v5: bias via 2-shift bf16 band, bf16x2 reads ----------------
#define LK 72
#define PSK 72   // Ps row spans 64 s-values; stride must be >= 64 (72 staggers banks)
__global__ __launch_bounds__(256)
void attn5_kernel(const bf16* __restrict__ Qg, const bf16* __restrict__ Kg,
                  const bf16* __restrict__ Vtg, const float* __restrict__ gate,
                  const float* __restrict__ pbt, bf16* __restrict__ ctx)
{
  __shared__ bf16 Ks[2][64 * LK];     // 18432 B
  __shared__ bf16 Vs[2][64 * LK];     // 18432 B
  __shared__ bf16 Ps[4][32 * PSK];    // 18432 B
  __shared__ bf16 pbs2[2][2184];      //  8736 B  (total 64032 B)

  const int t0 = blockIdx.x * 128;
  const int h  = blockIdx.y;
  const int b  = blockIdx.z;
  const int tid  = threadIdx.x;
  const int lane = tid & 63;
  const int wave = tid >> 6;
  const int qd = lane >> 4;
  const int lm = lane & 15;

  // pb_win[i] = pbt[h][i - t0 + 1920]; copy c: pbs2[c][j] = pb_win[j + c - 2]
  for (int j = tid; j < 2184; j += 256) {
#pragma unroll
    for (int c2 = 0; c2 < 2; c2++) {
      int gidx = j + c2 - 2 - t0 + 1920;
      pbs2[c2][j] = (bf16)((gidx >= 0 && gidx < NDELTA) ? pbt[h * NDELTA + gidx] : 0.0f);
    }
  }

  bf16x8 qf[2][2];
  float g[2];
#pragma unroll
  for (int nb = 0; nb < 2; nb++) {
    const int q = t0 + wave * 32 + nb * 16 + lm;
    const bf16* qrow = Qg + (size_t)(b * T_SEQ + q) * E_DIM + h * D_DIM;
    qf[nb][0] = *(const bf16x8*)(qrow + qd * 8);
    qf[nb][1] = *(const bf16x8*)(qrow + 32 + qd * 8);
    g[nb] = gate[((size_t)(b * H_NUM + h)) * T_SEQ + q];
  }

  // per-lane shift copy c (makes window base even) and base offset
  const int c = (lm + 1) & 1;
  const int ebase0 = 4 * qd + 129 - wave * 32 - lm - c;  // + s0 - nb*16 + 16*mb at use

  const int srow = tid >> 2;
  const int scol = (tid & 3) * 16;
  const bf16* kgp = Kg  + ((size_t)(b * T_SEQ) + srow) * E_DIM + h * D_DIM + scol;
  const bf16* vgp = Vtg + ((size_t)(b * 1024) + h * D_DIM + srow) * T_SEQ + scol;

  {
    bf16x8 a0 = *(const bf16x8*)kgp;
    bf16x8 a1 = *(const bf16x8*)(kgp + 8);
    bf16x8 c0 = *(const bf16x8*)vgp;
    bf16x8 c1 = *(const bf16x8*)(vgp + 8);
    *(bf16x8*)&Ks[0][srow * LK + scol]     = a0;
    *(bf16x8*)&Ks[0][srow * LK + scol + 8] = a1;
    *(bf16x8*)&Vs[0][srow * LK + scol]     = c0;
    *(bf16x8*)&Vs[0][srow * LK + scol + 8] = c1;
  }
  __syncthreads();

  f32x4 o[4][2] = {};
  float li[2] = {0.0f, 0.0f};
  bf16* psw = &Ps[wave][0];

  for (int it = 0; it < T_SEQ / 64; it++) {
    const int s0 = it * 64;
    const int buf = it & 1;
    const bool more = (it + 1 < T_SEQ / 64);
    bf16x8 nk0, nk1, nv0, nv1;
    if (more) {
      const bf16* kn = kgp + (size_t)(s0 + 64) * E_DIM;
      const bf16* vn = vgp + (s0 + 64);
      nk0 = *(const bf16x8*)kn; nk1 = *(const bf16x8*)(kn + 8);
      nv0 = *(const bf16x8*)vn; nv1 = *(const bf16x8*)(vn + 8);
    }

    bf16x8 kf[4][2];
#pragma unroll
    for (int mb = 0; mb < 4; mb++) {
      kf[mb][0] = *(const bf16x8*)&Ks[buf][(16 * mb + lm) * LK + qd * 8];
      kf[mb][1] = *(const bf16x8*)&Ks[buf][(16 * mb + lm) * LK + 32 + qd * 8];
    }
#pragma unroll
    for (int nb = 0; nb < 2; nb++) {
      f32x4 sc[4];
#pragma unroll
      for (int mb = 0; mb < 4; mb++) {
        f32x4 t = {};
        t = __builtin_amdgcn_mfma_f32_16x16x32_bf16(kf[mb][0], qf[nb][0], t, 0, 0, 0);
        t = __builtin_amdgcn_mfma_f32_16x16x32_bf16(kf[mb][1], qf[nb][1], t, 0, 0, 0);
        sc[mb] = t;
      }
      const int e0 = ebase0 + s0 - nb * 16;
      float rs = 0.0f;
#pragma unroll
      for (int mb = 0; mb < 4; mb++) {
        const bf16x2 bb0 = *(const bf16x2*)&pbs2[c][e0 + 16 * mb];
        const bf16x2 bb1 = *(const bf16x2*)&pbs2[c][e0 + 16 * mb + 2];
        const float bias4[4] = {(float)bb0[0], (float)bb0[1], (float)bb1[0], (float)bb1[1]};
        bf16x4 pk;
#pragma unroll
        for (int r = 0; r < 4; r++) {
          float p = __builtin_amdgcn_exp2f(sc[mb][r] + g[nb] * bias4[r]);
          rs += p;
          pk[r] = (bf16)p;
        }
        *(bf16x4*)&psw[(nb * 16 + lm) * PSK + 16 * mb + 4 * qd] = pk;
      }
      li[nb] += rs;
    }
    bf16x8 pf[2][2];
#pragma unroll
    for (int nb = 0; nb < 2; nb++) {
      pf[nb][0] = *(const bf16x8*)&psw[(nb * 16 + lm) * PSK + qd * 8];
      pf[nb][1] = *(const bf16x8*)&psw[(nb * 16 + lm) * PSK + 32 + qd * 8];
    }
#pragma unroll
    for (int db = 0; db < 4; db++) {
      bf16x8 vf0 = *(const bf16x8*)&Vs[buf][(16 * db + lm) * LK + qd * 8];
      bf16x8 vf1 = *(const bf16x8*)&Vs[buf][(16 * db + lm) * LK + 32 + qd * 8];
#pragma unroll
      for (int nb = 0; nb < 2; nb++) {
        o[db][nb] = __builtin_amdgcn_mfma_f32_16x16x32_bf16(vf0, pf[nb][0], o[db][nb], 0, 0, 0);
        o[db][nb] = __builtin_amdgcn_mfma_f32_16x16x32_bf16(vf1, pf[nb][1], o[db][nb], 0, 0, 0);
      }
    }
    if (more) {
      *(bf16x8*)&Ks[buf ^ 1][srow * LK + scol]     = nk0;
      *(bf16x8*)&Ks[buf ^ 1][srow * LK + scol + 8] = nk1;
      *(bf16x8*)&Vs[buf ^ 1][srow * LK + scol]     = nv0;
      *(bf16x8*)&Vs[buf ^ 1][srow * LK + scol + 8] = nv1;
    }
    __syncthreads();
  }

#pragma unroll
  for (int nb = 0; nb < 2; nb++) {
    li[nb] += __shfl_xor(li[nb], 16);
    li[nb] += __shfl_xor(li[nb], 32);
  }
#pragma unroll
  for (int nb = 0; nb < 2; nb++) {
    const float inv = 1.0f / li[nb];
    const int q = t0 + wave * 32 + nb * 16 + lm;
    bf16* obase = ctx + (size_t)(b * T_SEQ + q) * E_DIM + h * D_DIM + 4 * qd;
#pragma unroll
    for (int db = 0; db < 4; db++) {
      bf16x4 ov;
      ov[0] = (bf16)(o[db][nb][0] * inv); ov[1] = (bf16)(o[db][nb][1] * inv);
      ov[2] = (bf16)(o[db][nb][2] * inv); ov[3] = (bf16)(o[db][nb][3] * inv);
      *(bf16x4*)&obase[16 * db] = ov;
    }
  }
}

// ---------------- orchestration ----------------
extern "C" void kernel_launch(void* const* d_in, const int* in_sizes, int n_in,
                              void* d_out, int out_size, void* d_ws, size_t ws_size,
                              hipStream_t stream)
{
  const float* hs     = (const float*)d_in[0];
  const float* q_w    = (const float*)d_in[1];
  const float* q_b    = (const float*)d_in[2];
  const float* k_w    = (const float*)d_in[3];
  const float* k_b    = (const float*)d_in[4];
  const float* v_w    = (const float*)d_in[5];
  const float* v_b    = (const float*)d_in[6];
  const float* out_w  = (const float*)d_in[7];
  const float* out_b  = (const float*)d_in[8];
  const float* rel    = (const float*)d_in[9];
  const float* gconst = (const float*)d_in[10];
  const float* gru_w  = (const float*)d_in[11];
  const float* gru_b  = (const float*)d_in[12];

  char* p = (char*)d_ws;
  bf16* hsb  = (bf16*)p; p += (size_t)4096 * 1024 * 2;
  bf16* wcat = (bf16*)p; p += (size_t)3072 * 1024 * 2;
  bf16* wob  = (bf16*)p; p += (size_t)1024 * 1024 * 2;
  bf16* Qb   = (bf16*)p; p += (size_t)4096 * 1024 * 2;
  bf16* Kb   = (bf16*)p; p += (size_t)4096 * 1024 * 2;
  bf16* Vtb  = (bf16*)p; p += (size_t)2048 * 2048 * 2;
  bf16* ctxb = (bf16*)p; p += (size_t)4096 * 1024 * 2;
  float* gatep = (float*)p; p += (size_t)2 * H_NUM * T_SEQ * 4;
  float* pbt   = (float*)p; p += (size_t)H_NUM * NDELTA * 4;

  cast_bf16_kernel<<<4096, 256, 0, stream>>>(hs, hsb, 1048576);
  cast_w_kernel<<<dim3(1024, 4), 256, 0, stream>>>(q_w, k_w, v_w, out_w, wcat, wob);
  pb_kernel<<<64, 64, 0, stream>>>(rel, pbt);
  gate_kernel<<<256, 256, 0, stream>>>(hs, gru_w, gru_b, gconst, gatep);

  const float qalpha = 0.125f * LOG2E;
  gemm3_kernel<1, 128><<<dim3(24, 32), 256, 0, stream>>>(
      hsb, wcat, q_b, k_b, v_b, qalpha, Qb, Kb, Vtb);

  attn5_kernel<<<dim3(T_SEQ / 128, H_NUM, 2), 256, 0, stream>>>(Qb, Kb, Vtb, gatep, pbt, ctxb);

  gemm3_kernel<0, 64><<<dim3(8, 64), 256, 0, stream>>>(
      ctxb, wob, out_b, nullptr, nullptr, 1.0f, d_out, nullptr, nullptr);
}

// Round 10
// 229.926 us; speedup vs baseline: 1.1234x; 1.1234x over previous
//
#include <hip/hip_runtime.h>
#include <hip/hip_bf16.h>
#include <math.h>

typedef __bf16 bf16;
typedef __bf16 bf16x4 __attribute__((ext_vector_type(4)));
typedef __bf16 bf16x8 __attribute__((ext_vector_type(8)));
typedef float  f32x4  __attribute__((ext_vector_type(4)));

#define T_SEQ 2048
#define E_DIM 1024
#define H_NUM 16
#define D_DIM 64
#define NDELTA 4095
#define LOG2E 1.4426950408889634f

__device__ __forceinline__ void gld16(const bf16* g, bf16* l) {
  __builtin_amdgcn_global_load_lds((__attribute__((address_space(1))) void*)(g),
                                   (__attribute__((address_space(3))) void*)(l), 16, 0, 0);
}

// ---------------- fp32 -> bf16 cast (hidden_states) ----------------
__global__ void cast_bf16_kernel(const float* __restrict__ src, bf16* __restrict__ dst, int n4) {
  int i = blockIdx.x * blockDim.x + threadIdx.x;
  if (i >= n4) return;
  const float4 v = reinterpret_cast<const float4*>(src)[i];
  bf16x4 o;
  o[0] = (bf16)v.x; o[1] = (bf16)v.y; o[2] = (bf16)v.z; o[3] = (bf16)v.w;
  reinterpret_cast<bf16x4*>(dst)[i] = o;
}

// ---------------- all 4 weight casts in one launch; q/k/v into concat buffer ----------------
__global__ void cast_w_kernel(const float* __restrict__ q_w, const float* __restrict__ k_w,
                              const float* __restrict__ v_w, const float* __restrict__ o_w,
                              bf16* __restrict__ wcat, bf16* __restrict__ wob) {
  int i = blockIdx.x * 256 + threadIdx.x;
  int sel = blockIdx.y;
  const float* src = (sel == 0) ? q_w : (sel == 1) ? k_w : (sel == 2) ? v_w : o_w;
  bf16* dst = (sel < 3) ? (wcat + (size_t)sel * 1048576) : wob;
  const float4 v = reinterpret_cast<const float4*>(src)[i];
  bf16x4 o;
  o[0] = (bf16)v.x; o[1] = (bf16)v.y; o[2] = (bf16)v.z; o[3] = (bf16)v.w;
  reinterpret_cast<bf16x4*>(dst)[i] = o;
}

// ---------------- position-bias table pbt[h][delta+2047] ----------------
__global__ void pb_kernel(const float* __restrict__ rel_embed, float* __restrict__ pbt) {
  int dd = blockIdx.x * 64 + threadIdx.x;
  if (dd >= NDELTA) return;
  int delta = dd - (T_SEQ - 1);
  int bucket = (delta > 0) ? 160 : 0;
  int rel = abs(delta);
  int v;
  if (rel < 80) {
    v = rel;
  } else {
    float rf = (float)(rel < 1 ? 1 : rel);
    float lf = logf(rf / 80.0f) * (80.0f / 2.302585092994046f);
    int lg = 80 + (int)lf;
    v = lg < 159 ? lg : 159;
  }
  bucket += v;
#pragma unroll
  for (int h = 0; h < H_NUM; h++)
    pbt[h * NDELTA + dd] = rel_embed[bucket * H_NUM + h];
}

// ---------------- gate (output pre-multiplied by LOG2E) ----------------
__global__ __launch_bounds__(256)
void gate_kernel(const float* __restrict__ hs, const float* __restrict__ gru_w,
                 const float* __restrict__ gru_b, const float* __restrict__ gconst,
                 float* __restrict__ gate)
{
  __shared__ float w[512];
  int tid = threadIdx.x;
  w[tid] = gru_w[tid];
  w[tid + 256] = gru_w[tid + 256];
  __syncthreads();
  int idx = blockIdx.x * 256 + tid;
  int h  = idx & 15;
  int bt = idx >> 4;
  const float* x = hs + (size_t)bt * E_DIM + h * D_DIM;
  float acc[8] = {0,0,0,0,0,0,0,0};
  for (int d = 0; d < 64; d += 4) {
    float4 xv = *(const float4*)&x[d];
#pragma unroll
    for (int e = 0; e < 8; e++) {
      acc[e] += xv.x * w[e*64+d] + xv.y * w[e*64+d+1]
              + xv.z * w[e*64+d+2] + xv.w * w[e*64+d+3];
    }
  }
  float p0 = acc[0]+acc[1]+acc[2]+acc[3] + gru_b[0]+gru_b[1]+gru_b[2]+gru_b[3];
  float p1 = acc[4]+acc[5]+acc[6]+acc[7] + gru_b[4]+gru_b[5]+gru_b[6]+gru_b[7];
  float ga = 1.0f / (1.0f + expf(-p0));
  float gb = 1.0f / (1.0f + expf(-p1));
  float g = (ga * (gb * gconst[h] - 1.0f) + 2.0f) * LOG2E;
  int bb = bt >> 11;
  int t  = bt & (T_SEQ - 1);
  gate[((size_t)(bb * H_NUM + h)) * T_SEQ + t] = g;
}

// ---------------- GEMM v4: dbuf global_load_lds, BM x BN x 32, high-occupancy tiles ----------------
// MODE 0: O-proj -> f32 out0, bias b0.  MODE 1: fused QKV (BN=128), seg = n0>>10.
template<int MODE, int BM, int BN>
__global__ __launch_bounds__(256, 4)
void gemm4_kernel(const bf16* __restrict__ A, const bf16* __restrict__ W,
                  const float* __restrict__ b0, const float* __restrict__ b1,
                  const float* __restrict__ b2, float qalpha,
                  void* __restrict__ out0, void* __restrict__ out1, void* __restrict__ out2)
{
  constexpr int AM = BM / 32;          // m-frags per wave (wave covers BM/2 rows)
  constexpr int AN = BN / 32;          // n-frags per wave
  __shared__ bf16 As[2][BM * 32];
  __shared__ bf16 Bs[2][BN * 32];
  const int tid  = threadIdx.x;
  const int lane = tid & 63;
  const int wave = tid >> 6;
  const int m0 = blockIdx.y * BM;
  const int n0 = blockIdx.x * BN;
  const int wm = (wave >> 1) * (BM / 2);
  const int wn = (wave & 1) * (BN / 2);
  const int qd = lane >> 4;
  const int lm = lane & 15;

  const int row4 = lane >> 2;          // 0..15
  const int col8 = (lane & 3) * 8;
  // A: BM/64 gld16 per thread; B: BN/64 per thread. Wave w stages rows w*(BM/4)..
  const bf16* gA0 = A + (size_t)(m0 + wave * (BM / 4) + row4) * 1024 + col8;
  const bf16* gB0 = W + (size_t)(n0 + wave * (BN / 4) + row4) * 1024 + col8;
  bf16* lA = (bf16*)As + wave * (BM / 4) * 32;
  bf16* lB = (bf16*)Bs + wave * (BN / 4) * 32;

  // stage k0=0 into buf 0
  gld16(gA0, lA);
  if (BM == 128) gld16(gA0 + (size_t)16 * 1024, lA + 512);
  gld16(gB0, lB);
  if (BN == 128) gld16(gB0 + (size_t)16 * 1024, lB + 512);
  __syncthreads();

  f32x4 acc[AM][AN] = {};

  for (int k0 = 0; k0 < 1024; k0 += 32) {
    const int buf = (k0 >> 5) & 1;
    if (k0 + 32 < 1024) {   // prefetch next tile into the other buffer
      bf16* lA1 = lA + (buf ^ 1) * (BM * 32);
      bf16* lB1 = lB + (buf ^ 1) * (BN * 32);
      gld16(gA0 + k0 + 32, lA1);
      if (BM == 128) gld16(gA0 + (size_t)16 * 1024 + k0 + 32, lA1 + 512);
      gld16(gB0 + k0 + 32, lB1);
      if (BN == 128) gld16(gB0 + (size_t)16 * 1024 + k0 + 32, lB1 + 512);
    }
    bf16x8 af[AM], bfr[AN];
#pragma unroll
    for (int i = 0; i < AM; i++)
      af[i]  = *(const bf16x8*)&As[buf][(wm + i * 16 + lm) * 32 + qd * 8];
#pragma unroll
    for (int i = 0; i < AN; i++)
      bfr[i] = *(const bf16x8*)&Bs[buf][(wn + i * 16 + lm) * 32 + qd * 8];
#pragma unroll
    for (int im = 0; im < AM; im++)
#pragma unroll
      for (int in = 0; in < AN; in++)
        acc[im][in] = __builtin_amdgcn_mfma_f32_16x16x32_bf16(af[im], bfr[in], acc[im][in], 0, 0, 0);
    __syncthreads();   // drains vmcnt (prefetch landed) + lgkm (frag reads done)
  }

  const int seg = n0 >> 10;
  const float* bias = (MODE == 0) ? b0 : (seg == 0 ? b0 : (seg == 1 ? b1 : b2));
  const float alpha = (MODE == 1 && seg == 0) ? qalpha : 1.0f;

#pragma unroll
  for (int im = 0; im < AM; im++) {
#pragma unroll
    for (int in = 0; in < AN; in++) {
      const int n  = n0 + wn + in * 16 + lm;
      const int n1 = n & 1023;
      const float bv = bias[n1];
      const int mb = m0 + wm + im * 16 + qd * 4;
      if (MODE == 0) {
        float* o = (float*)out0;
#pragma unroll
        for (int r = 0; r < 4; r++)
          o[(size_t)(mb + r) * 1024 + n1] = acc[im][in][r] + bv;
      } else if (seg == 2) {
        const int bb = mb >> 11;
        const int t  = mb & 2047;
        bf16x4 pk;
#pragma unroll
        for (int r = 0; r < 4; r++) pk[r] = (bf16)(acc[im][in][r] + bv);
        *(bf16x4*)&((bf16*)out2)[((size_t)(bb * 1024 + n1)) * 2048 + t] = pk;
      } else {
        bf16* o = (bf16*)(seg == 0 ? out0 : out1);
#pragma unroll
        for (int r = 0; r < 4; r++)
          o[(size_t)(mb + r) * 1024 + n1] = (bf16)((acc[im][in][r] + bv) * alpha);
      }
    }
  }
}

// ---------------- flash attention v3 (round-6 proven version, verbatim) ----------------
#define LK 72
__global__ __launch_bounds__(256)
void attn3_kernel(const bf16* __restrict__ Qg, const bf16* __restrict__ Kg,
                  const bf16* __restrict__ Vtg, const float* __restrict__ gate,
                  const float* __restrict__ pbt, bf16* __restrict__ ctx)
{
  __shared__ bf16 Ks[2][64 * LK];
  __shared__ bf16 Vs[2][64 * LK];
  __shared__ bf16 Ps[4][32 * LK];
  __shared__ float pbs[2176];

  const int t0 = blockIdx.x * 128;
  const int h  = blockIdx.y;
  const int b  = blockIdx.z;
  const int tid  = threadIdx.x;
  const int lane = tid & 63;
  const int wave = tid >> 6;
  const int qd = lane >> 4;
  const int lm = lane & 15;

  for (int i = tid; i < 2176; i += 256) {
    int idx = i - t0 + 1920;
    pbs[i] = (idx >= 0 && idx < NDELTA) ? pbt[h * NDELTA + idx] : 0.0f;
  }

  bf16x8 qf[2][2];
  float g[2];
#pragma unroll
  for (int nb = 0; nb < 2; nb++) {
    const int q = t0 + wave * 32 + nb * 16 + lm;
    const bf16* qrow = Qg + (size_t)(b * T_SEQ + q) * E_DIM + h * D_DIM;
    qf[nb][0] = *(const bf16x8*)(qrow + qd * 8);
    qf[nb][1] = *(const bf16x8*)(qrow + 32 + qd * 8);
    g[nb] = gate[((size_t)(b * H_NUM + h)) * T_SEQ + q];
  }

  const int srow = tid >> 2;
  const int scol = (tid & 3) * 16;
  const bf16* kgp = Kg  + ((size_t)(b * T_SEQ) + srow) * E_DIM + h * D_DIM + scol;
  const bf16* vgp = Vtg + ((size_t)(b * 1024) + h * D_DIM + srow) * T_SEQ + scol;

  {
    bf16x8 a0 = *(const bf16x8*)kgp;
    bf16x8 a1 = *(const bf16x8*)(kgp + 8);
    bf16x8 c0 = *(const bf16x8*)vgp;
    bf16x8 c1 = *(const bf16x8*)(vgp + 8);
    *(bf16x8*)&Ks[0][srow * LK + scol]     = a0;
    *(bf16x8*)&Ks[0][srow * LK + scol + 8] = a1;
    *(bf16x8*)&Vs[0][srow * LK + scol]     = c0;
    *(bf16x8*)&Vs[0][srow * LK + scol + 8] = c1;
  }
  __syncthreads();

  f32x4 o[4][2] = {};
  float li[2] = {0.0f, 0.0f};
  bf16* psw = &Ps[wave][0];

  for (int it = 0; it < T_SEQ / 64; it++) {
    const int s0 = it * 64;
    const int buf = it & 1;
    const bool more = (it + 1 < T_SEQ / 64);
    bf16x8 nk0, nk1, nv0, nv1;
    if (more) {
      const bf16* kn = kgp + (size_t)(s0 + 64) * E_DIM;
      const bf16* vn = vgp + (s0 + 64);
      nk0 = *(const bf16x8*)kn; nk1 = *(const bf16x8*)(kn + 8);
      nv0 = *(const bf16x8*)vn; nv1 = *(const bf16x8*)(vn + 8);
    }

    bf16x8 kf[4][2];
#pragma unroll
    for (int mb = 0; mb < 4; mb++) {
      kf[mb][0] = *(const bf16x8*)&Ks[buf][(16 * mb + lm) * LK + qd * 8];
      kf[mb][1] = *(const bf16x8*)&Ks[buf][(16 * mb + lm) * LK + 32 + qd * 8];
    }
#pragma unroll
    for (int nb = 0; nb < 2; nb++) {
      f32x4 sc[4];
#pragma unroll
      for (int mb = 0; mb < 4; mb++) {
        f32x4 t = {};
        t = __builtin_amdgcn_mfma_f32_16x16x32_bf16(kf[mb][0], qf[nb][0], t, 0, 0, 0);
        t = __builtin_amdgcn_mfma_f32_16x16x32_bf16(kf[mb][1], qf[nb][1], t, 0, 0, 0);
        sc[mb] = t;
      }
      const int ib = s0 + 4 * qd + 127 - (wave * 32 + nb * 16 + lm);
      float rs = 0.0f;
#pragma unroll
      for (int mb = 0; mb < 4; mb++) {
        bf16x4 pk;
#pragma unroll
        for (int r = 0; r < 4; r++) {
          float p = __builtin_amdgcn_exp2f(sc[mb][r] + g[nb] * pbs[ib + 16 * mb + r]);
          rs += p;
          pk[r] = (bf16)p;
        }
        *(bf16x4*)&psw[(nb * 16 + lm) * LK + 16 * mb + 4 * qd] = pk;
      }
      li[nb] += rs;
    }
    bf16x8 pf[2][2];
#pragma unroll
    for (int nb = 0; nb < 2; nb++) {
      pf[nb][0] = *(const bf16x8*)&psw[(nb * 16 + lm) * LK + qd * 8];
      pf[nb][1] = *(const bf16x8*)&psw[(nb * 16 + lm) * LK + 32 + qd * 8];
    }
#pragma unroll
    for (int db = 0; db < 4; db++) {
      bf16x8 vf0 = *(const bf16x8*)&Vs[buf][(16 * db + lm) * LK + qd * 8];
      bf16x8 vf1 = *(const bf16x8*)&Vs[buf][(16 * db + lm) * LK + 32 + qd * 8];
#pragma unroll
      for (int nb = 0; nb < 2; nb++) {
        o[db][nb] = __builtin_amdgcn_mfma_f32_16x16x32_bf16(vf0, pf[nb][0], o[db][nb], 0, 0, 0);
        o[db][nb] = __builtin_amdgcn_mfma_f32_16x16x32_bf16(vf1, pf[nb][1], o[db][nb], 0, 0, 0);
      }
    }
    if (more) {
      *(bf16x8*)&Ks[buf ^ 1][srow * LK + scol]     = nk0;
      *(bf16x8*)&Ks[buf ^ 1][srow * LK + scol + 8] = nk1;
      *(bf16x8*)&Vs[buf ^ 1][srow * LK + scol]     = nv0;
      *(bf16x8*)&Vs[buf ^ 1][srow * LK + scol + 8] = nv1;
    }
    __syncthreads();
  }

#pragma unroll
  for (int nb = 0; nb < 2; nb++) {
    li[nb] += __shfl_xor(li[nb], 16);
    li[nb] += __shfl_xor(li[nb], 32);
  }
#pragma unroll
  for (int nb = 0; nb < 2; nb++) {
    const float inv = 1.0f / li[nb];
    const int q = t0 + wave * 32 + nb * 16 + lm;
    bf16* obase = ctx + (size_t)(b * T_SEQ + q) * E_DIM + h * D_DIM + 4 * qd;
#pragma unroll
    for (int db = 0; db < 4; db++) {
      bf16x4 ov;
      ov[0] = (bf16)(o[db][nb][0] * inv); ov[1] = (bf16)(o[db][nb][1] * inv);
      ov[2] = (bf16)(o[db][nb][2] * inv); ov[3] = (bf16)(o[db][nb][3] * inv);
      *(bf16x4*)&obase[16 * db] = ov;
    }
  }
}

// ---------------- orchestration ----------------
extern "C" void kernel_launch(void* const* d_in, const int* in_sizes, int n_in,
                              void* d_out, int out_size, void* d_ws, size_t ws_size,
                              hipStream_t stream)
{
  const float* hs     = (const float*)d_in[0];
  const float* q_w    = (const float*)d_in[1];
  const float* q_b    = (const float*)d_in[2];
  const float* k_w    = (const float*)d_in[3];
  const float* k_b    = (const float*)d_in[4];
  const float* v_w    = (const float*)d_in[5];
  const float* v_b    = (const float*)d_in[6];
  const float* out_w  = (const float*)d_in[7];
  const float* out_b  = (const float*)d_in[8];
  const float* rel    = (const float*)d_in[9];
  const float* gconst = (const float*)d_in[10];
  const float* gru_w  = (const float*)d_in[11];
  const float* gru_b  = (const float*)d_in[12];

  char* p = (char*)d_ws;
  bf16* hsb  = (bf16*)p; p += (size_t)4096 * 1024 * 2;
  bf16* wcat = (bf16*)p; p += (size_t)3072 * 1024 * 2;
  bf16* wob  = (bf16*)p; p += (size_t)1024 * 1024 * 2;
  bf16* Qb   = (bf16*)p; p += (size_t)4096 * 1024 * 2;
  bf16* Kb   = (bf16*)p; p += (size_t)4096 * 1024 * 2;
  bf16* Vtb  = (bf16*)p; p += (size_t)2048 * 2048 * 2;
  bf16* ctxb = (bf16*)p; p += (size_t)4096 * 1024 * 2;
  float* gatep = (float*)p; p += (size_t)2 * H_NUM * T_SEQ * 4;
  float* pbt   = (float*)p; p += (size_t)H_NUM * NDELTA * 4;

  cast_bf16_kernel<<<4096, 256, 0, stream>>>(hs, hsb, 1048576);
  cast_w_kernel<<<dim3(1024, 4), 256, 0, stream>>>(q_w, k_w, v_w, out_w, wcat, wob);
  pb_kernel<<<64, 64, 0, stream>>>(rel, pbt);
  gate_kernel<<<256, 256, 0, stream>>>(hs, gru_w, gru_b, gconst, gatep);

  const float qalpha = 0.125f * LOG2E;
  // QKV: 64x128 tiles -> grid 24 x 64 = 1536 blocks (~6/CU avail, 4/CU resident)
  gemm4_kernel<1, 64, 128><<<dim3(24, 64), 256, 0, stream>>>(
      hsb, wcat, q_b, k_b, v_b, qalpha, Qb, Kb, Vtb);

  attn3_kernel<<<dim3(T_SEQ / 128, H_NUM, 2), 256, 0, stream>>>(Qb, Kb, Vtb, gatep, pbt, ctxb);

  // O-proj: 64x64 tiles -> grid 16 x 64 = 1024 blocks (4/CU)
  gemm4_kernel<0, 64, 64><<<dim3(16, 64), 256, 0, stream>>>(
      ctxb, wob, out_b, nullptr, nullptr, 1.0f, d_out, nullptr, nullptr);
}